// Round 8
// baseline (2321.051 us; speedup 1.0000x reference)
//
#include <hip/hip_runtime.h>
#include <math.h>

#define NN 50000
#define NE 600000
#define HID 128
#define NCLS 10

#define NT 64     // nodes per fused-layer block
#define AGS 132   // Agg row stride in floats (mult of 4 for float4 writes)
#define LBK 32    // W k-chunk staged in LDS

// ================= graph prep: CSR by destination =================

__global__ __launch_bounds__(256) void k_zero(int* __restrict__ p, int n) {
    int i = blockIdx.x * 256 + threadIdx.x;
    if (i < n) p[i] = 0;
}

__global__ __launch_bounds__(256) void k_count(const int* __restrict__ edge,
                                               int* __restrict__ counts) {
    int e = blockIdx.x * 256 + threadIdx.x;
    if (e < NE) atomicAdd(&counts[edge[NE + e]], 1);
}

__device__ __forceinline__ int wave_incl_scan(int x, int lane) {
#pragma unroll
    for (int off = 1; off < 64; off <<= 1) {
        int y = __shfl_up(x, off, 64);
        if (lane >= off) x += y;
    }
    return x;
}

__global__ __launch_bounds__(256) void k_scan1(const int* __restrict__ counts,
                                               int* __restrict__ rowptr,
                                               int* __restrict__ bsum,
                                               float* __restrict__ dinv) {
    __shared__ int ws[4];
    int tid = threadIdx.x;
    int i = blockIdx.x * 256 + tid;
    int lane = tid & 63, wv = tid >> 6;
    int v = (i < NN) ? counts[i] : 0;
    if (i < NN) dinv[i] = rsqrtf((float)(v + 1));
    int x = wave_incl_scan(v, lane);
    if (lane == 63) ws[wv] = x;
    __syncthreads();
    int off = 0;
    for (int j = 0; j < wv; ++j) off += ws[j];
    if (i < NN) rowptr[i] = off + x - v;
    if (tid == 255) bsum[blockIdx.x] = off + x;
}

__global__ __launch_bounds__(256) void k_scan2(int* __restrict__ bsum, int n) {
    __shared__ int ws[4];
    int tid = threadIdx.x;
    int lane = tid & 63, wv = tid >> 6;
    int v = (tid < n) ? bsum[tid] : 0;
    int x = wave_incl_scan(v, lane);
    if (lane == 63) ws[wv] = x;
    __syncthreads();
    int off = 0;
    for (int j = 0; j < wv; ++j) off += ws[j];
    __syncthreads();
    if (tid < n) bsum[tid] = off + x - v;
}

// also zeroes the cursor array for k_fill (saves one dispatch)
__global__ __launch_bounds__(256) void k_scan3(int* __restrict__ rowptr,
                                               const int* __restrict__ bsum,
                                               int* __restrict__ cursor) {
    int i = blockIdx.x * 256 + threadIdx.x;
    if (i < NN) {
        rowptr[i] += bsum[blockIdx.x];
        cursor[i] = 0;
    }
    if (i == 0) rowptr[NN] = NE;
}

__global__ __launch_bounds__(256) void k_fill(const int* __restrict__ edge,
                                              const int* __restrict__ rowptr,
                                              int* __restrict__ cursor,
                                              const float* __restrict__ dinv,
                                              int2* __restrict__ csr) {
    int e = blockIdx.x * 256 + threadIdx.x;
    if (e >= NE) return;
    int s = edge[e], d = edge[NE + e];
    int p = rowptr[d] + atomicAdd(&cursor[d], 1);
    csr[p] = make_int2(s, __float_as_int(dinv[s] * dinv[d]));
}

// ================= fused GCN layer (aggregate-first) =================
// ELU(A·(H·W)+b) == ELU((A·H)·W+b): phase A gathers (A·H) rows for 64 nodes
// straight into LDS; phase B does the 64x128x128 matmul from LDS with W staged
// in 32-k chunks (loads overlapped with FMA), fused bias+ELU, one global write.
// LDS = 64*132*4 + 32*128*4 = 49.8 KB -> 3 blocks/CU.

__global__ __launch_bounds__(256) void k_layer(const float* __restrict__ Hin,
                                               float* __restrict__ Hout,
                                               const float* __restrict__ W,
                                               const float* __restrict__ bias,
                                               const int* __restrict__ rowptr,
                                               const int2* __restrict__ csr,
                                               const float* __restrict__ dinv) {
    __shared__ float Agg[NT * AGS];    // (A·H) tile, row-major
    __shared__ float Bs[LBK * 128];    // W chunk, k-major
    int tid = threadIdx.x;
    int wv = tid >> 6, lane = tid & 63;
    int nodeBase = blockIdx.x * NT;

    // ---- phase A: gather; wave = 16 nodes, 2 edge slots x 32 lanes x float4 ----
    {
        int slot = lane >> 5;  // 0/1
        int l32 = lane & 31;   // float4 index within 128-col row
        const int2 zed = make_int2(0, 0);
        for (int n = 0; n < 16; ++n) {
            int node = nodeBase + wv * 16 + n;  // wave-uniform
            if (node >= NN) break;
            int beg = rowptr[node], end = rowptr[node + 1];
            float4 acc = {0.f, 0.f, 0.f, 0.f};
            if (slot == 0) {  // self-loop
                float sn = dinv[node];
                sn *= sn;
                float4 h = ((const float4*)(Hin + (size_t)node * HID))[l32];
                acc.x = sn * h.x; acc.y = sn * h.y; acc.z = sn * h.z; acc.w = sn * h.w;
            }
            int i = beg + slot;
            int2 e = (i < end) ? csr[i] : zed;
            while (i < end) {
                int2 en = (i + 2 < end) ? csr[i + 2] : zed;  // one-ahead prefetch
                float4 v = ((const float4*)(Hin + (size_t)e.x * HID))[l32];
                float w = __int_as_float(e.y);
                acc.x += w * v.x; acc.y += w * v.y; acc.z += w * v.z; acc.w += w * v.w;
                e = en;
                i += 2;
            }
            acc.x += __shfl_xor(acc.x, 32, 64);
            acc.y += __shfl_xor(acc.y, 32, 64);
            acc.z += __shfl_xor(acc.z, 32, 64);
            acc.w += __shfl_xor(acc.w, 32, 64);
            if (slot == 0)
                *(float4*)&Agg[(wv * 16 + n) * AGS + l32 * 4] = acc;
        }
    }
    // issue W chunk-0 loads before the barrier so latency overlaps barrier wait
    const float4* w0 = (const float4*)W;
    float4 c0 = w0[tid], c1 = w0[tid + 256], c2 = w0[tid + 512], c3 = w0[tid + 768];
    __syncthreads();  // Agg complete; Bs free
    ((float4*)Bs)[tid] = c0;
    ((float4*)Bs)[tid + 256] = c1;
    ((float4*)Bs)[tid + 512] = c2;
    ((float4*)Bs)[tid + 768] = c3;

    // ---- phase B: 64x128 tile matmul from LDS ----
    int wr = lane >> 3, wc = lane & 7;
    int wy = wv >> 1, wx = wv & 1;
    int lr0 = wy * 32 + wr * 4;   // 4 rows
    int lc0 = wx * 64 + wc * 8;   // 8 cols

    float acc[4][8];
#pragma unroll
    for (int i = 0; i < 4; ++i)
#pragma unroll
        for (int j = 0; j < 8; ++j) acc[i][j] = 0.f;

    for (int t = 0; t < 4; ++t) {
        __syncthreads();  // Bs chunk t visible
        float4 n0, n1, n2, n3;
        if (t < 3) {  // next chunk's loads ride behind this chunk's FMAs
            const float4* wn = (const float4*)(W + (size_t)(t + 1) * LBK * HID);
            n0 = wn[tid]; n1 = wn[tid + 256]; n2 = wn[tid + 512]; n3 = wn[tid + 768];
        }
#pragma unroll
        for (int kk = 0; kk < LBK; ++kk) {
            int k = t * LBK + kk;
            float a0 = Agg[(lr0 + 0) * AGS + k];
            float a1 = Agg[(lr0 + 1) * AGS + k];
            float a2 = Agg[(lr0 + 2) * AGS + k];
            float a3 = Agg[(lr0 + 3) * AGS + k];
            float b[8];
            ((float4*)b)[0] = *(const float4*)&Bs[kk * 128 + lc0];
            ((float4*)b)[1] = *(const float4*)&Bs[kk * 128 + lc0 + 4];
#pragma unroll
            for (int j = 0; j < 8; ++j) {
                acc[0][j] += a0 * b[j];
                acc[1][j] += a1 * b[j];
                acc[2][j] += a2 * b[j];
                acc[3][j] += a3 * b[j];
            }
        }
        if (t < 3) {
            __syncthreads();  // all readers done with chunk t
            ((float4*)Bs)[tid] = n0;
            ((float4*)Bs)[tid + 256] = n1;
            ((float4*)Bs)[tid + 512] = n2;
            ((float4*)Bs)[tid + 768] = n3;
        }
    }

    float4 bb0 = *(const float4*)(bias + lc0);
    float4 bb1 = *(const float4*)(bias + lc0 + 4);
#pragma unroll
    for (int i = 0; i < 4; ++i) {
        int gr = nodeBase + lr0 + i;
        if (gr < NN) {
            float4 o0, o1;
            o0.x = acc[i][0] + bb0.x; o0.y = acc[i][1] + bb0.y;
            o0.z = acc[i][2] + bb0.z; o0.w = acc[i][3] + bb0.w;
            o1.x = acc[i][4] + bb1.x; o1.y = acc[i][5] + bb1.y;
            o1.z = acc[i][6] + bb1.z; o1.w = acc[i][7] + bb1.w;
            o0.x = o0.x > 0.f ? o0.x : expm1f(o0.x);
            o0.y = o0.y > 0.f ? o0.y : expm1f(o0.y);
            o0.z = o0.z > 0.f ? o0.z : expm1f(o0.z);
            o0.w = o0.w > 0.f ? o0.w : expm1f(o0.w);
            o1.x = o1.x > 0.f ? o1.x : expm1f(o1.x);
            o1.y = o1.y > 0.f ? o1.y : expm1f(o1.y);
            o1.z = o1.z > 0.f ? o1.z : expm1f(o1.z);
            o1.w = o1.w > 0.f ? o1.w : expm1f(o1.w);
            float4* dst = (float4*)(Hout + (size_t)gr * HID + lc0);
            dst[0] = o0;
            dst[1] = o1;
        }
    }
}

// ================= output layer (128 -> 10), transform-first =================
// T2 is only 2 MB -> its random gather is L2-cheap; keep transform-first here.

__global__ __launch_bounds__(256) void k_matmul_out(const float* __restrict__ H,
                                                    const float* __restrict__ W,
                                                    float* __restrict__ T2) {
    __shared__ float Ws[128 * 11];
    int tid = threadIdx.x;
    for (int m = tid; m < HID * NCLS; m += 256) {
        int k = m / NCLS, c = m - k * NCLS;
        Ws[k * 11 + c] = W[m];
    }
    __syncthreads();
    int row = (blockIdx.x * 256 + tid) >> 4;
    int c16 = tid & 15;
    if (row >= NN) return;
    const float* h = H + (size_t)row * HID;
    float acc[NCLS];
#pragma unroll
    for (int c = 0; c < NCLS; ++c) acc[c] = 0.f;
#pragma unroll
    for (int j = 0; j < 8; ++j) {
        float hv = h[c16 + 16 * j];
        const float* wr = &Ws[(c16 + 16 * j) * 11];
#pragma unroll
        for (int c = 0; c < NCLS; ++c) acc[c] += hv * wr[c];
    }
#pragma unroll
    for (int off = 8; off >= 1; off >>= 1) {
#pragma unroll
        for (int c = 0; c < NCLS; ++c) acc[c] += __shfl_xor(acc[c], off, 16);
    }
    if (c16 < NCLS) T2[(size_t)row * NCLS + c16] = acc[c16];
}

__global__ __launch_bounds__(256) void k_gather_out(const float* __restrict__ T2,
                                                    float* __restrict__ out,
                                                    const int* __restrict__ rowptr,
                                                    const int2* __restrict__ csr,
                                                    const float* __restrict__ dinv,
                                                    const float* __restrict__ bias) {
    int lane = threadIdx.x & 63;
    int node = (blockIdx.x * 256 + threadIdx.x) >> 6;
    if (node >= NN) return;
    int slot = lane >> 4, c = lane & 15;
    int beg = rowptr[node], end = rowptr[node + 1];
    float acc = 0.f;
    if (c < NCLS) {
        for (int i = beg + slot; i < end; i += 4) {
            int2 e = csr[i];
            acc += __int_as_float(e.y) * T2[(size_t)e.x * NCLS + c];
        }
    }
    acc += __shfl_xor(acc, 16, 64);
    acc += __shfl_xor(acc, 32, 64);
    if (slot == 0 && c < NCLS) {
        float sn = dinv[node];
        sn *= sn;
        out[node * NCLS + c] = acc + sn * T2[(size_t)node * NCLS + c] + bias[c];
    }
}

// ================= launch =================

extern "C" void kernel_launch(void* const* d_in, const int* in_sizes, int n_in,
                              void* d_out, int out_size, void* d_ws, size_t ws_size,
                              hipStream_t stream) {
    (void)in_sizes; (void)n_in; (void)out_size; (void)ws_size;
    const float* x       = (const float*)d_in[0];
    const int*   edge    = (const int*)d_in[1];   // [2, NE] int32
    const float* W_stack = (const float*)d_in[2];
    const float* b_stack = (const float*)d_in[3];
    const float* W_out   = (const float*)d_in[4];
    const float* b_out   = (const float*)d_in[5];
    float* out = (float*)d_out;

    char* ws = (char*)d_ws;
    const size_t bigbuf = (size_t)NN * HID * sizeof(float);  // 25.6 MB
    float* X      = (float*)ws;
    float* Y      = (float*)(ws + bigbuf);
    char*  p      = ws + 2 * bigbuf;
    int2*  csr    = (int2*)p;              p += sizeof(int2) * NE;
    float* dinv   = (float*)p;             p += sizeof(float) * NN;
    int*   rowptr = (int*)p;               p += sizeof(int) * (NN + 1);
    int*   counts = (int*)p;               p += sizeof(int) * NN;    // also cursor
    int*   bsum   = (int*)p;               p += sizeof(int) * 256;

    const int NB_N  = (NN + 255) / 256;       // 196
    const int NB_E  = (NE + 255) / 256;
    const int NB_L  = (NN + NT - 1) / NT;     // 782
    const int NB_W  = (NN * 64 + 255) / 256;
    const int NB_O  = (NN * 16 + 255) / 256;

    // ---- CSR build (per call) ----
    k_zero<<<NB_N, 256, 0, stream>>>(counts, NN);
    k_count<<<NB_E, 256, 0, stream>>>(edge, counts);
    k_scan1<<<NB_N, 256, 0, stream>>>(counts, rowptr, bsum, dinv);
    k_scan2<<<1, 256, 0, stream>>>(bsum, NB_N);
    k_scan3<<<NB_N, 256, 0, stream>>>(rowptr, bsum, counts);
    k_fill<<<NB_E, 256, 0, stream>>>(edge, rowptr, counts, dinv, csr);

    // ---- 8 fused hidden layers (aggregate-first) ----
    const float* Hin = x;
    float* bufs[2] = {X, Y};
    for (int l = 0; l < 8; ++l) {
        float* Ho = bufs[l & 1];
        k_layer<<<NB_L, 256, 0, stream>>>(Hin, Ho,
                                          W_stack + (size_t)l * HID * HID,
                                          b_stack + (size_t)l * HID,
                                          rowptr, csr, dinv);
        Hin = Ho;
    }

    // ---- output layer (transform-first; Hin == Y after layer 7) ----
    k_matmul_out<<<NB_O, 256, 0, stream>>>(Hin, W_out, X);
    k_gather_out<<<NB_W, 256, 0, stream>>>(X, out, rowptr, csr, dinv, b_out);
}

// Round 9
// 1814.670 us; speedup vs baseline: 1.2790x; 1.2790x over previous
//
#include <hip/hip_runtime.h>
#include <hip/hip_cooperative_groups.h>
#include <math.h>

namespace cg = cooperative_groups;

#define NN 50000
#define NE 600000
#define HID 128
#define NCLS 10
#define BK 32
#define NCHUNK 196   // (NN+255)/256
#define NGRP16 3125  // NN/16
#define NGRP4 12500  // NN/4

typedef float v4f __attribute__((ext_vector_type(4)));
typedef int v2i __attribute__((ext_vector_type(2)));

__device__ __forceinline__ void nt_store4(const float4& v, float* p) {
    v4f t = {v.x, v.y, v.z, v.w};
    __builtin_nontemporal_store(t, (v4f*)p);
}

__device__ __forceinline__ int wave_incl_scan(int x, int lane) {
#pragma unroll
    for (int off = 1; off < 64; off <<= 1) {
        int y = __shfl_up(x, off, 64);
        if (lane >= off) x += y;
    }
    return x;
}

// ================= cooperative prep: CSR build in ONE dispatch =================
// All phases are register-thin; grid.sync between them. (Round-6 lesson: never
// put the register-fat GEMM in here.)

__global__ __launch_bounds__(256, 4) void k_prep(const int* __restrict__ edge,
                                                 int* __restrict__ counts,
                                                 int* __restrict__ rowptr,
                                                 int* __restrict__ bsum,
                                                 float* __restrict__ dinv,
                                                 int2* __restrict__ csr) {
    cg::grid_group gg = cg::this_grid();
    __shared__ int ws[4];
    int tid = threadIdx.x, bid = blockIdx.x;
    int gsz = gridDim.x * 256, gtid = bid * 256 + tid;
    int lane = tid & 63, wv = tid >> 6;

    // P0: zero counts
    for (int i = gtid; i < NN; i += gsz) counts[i] = 0;
    gg.sync();
    // P1: degree count on dst
    for (int e = gtid; e < NE; e += gsz) atomicAdd(&counts[edge[NE + e]], 1);
    gg.sync();
    // P2: per-chunk exclusive scan + dinv
    for (int c = bid; c < NCHUNK; c += gridDim.x) {
        int i = c * 256 + tid;
        int v = (i < NN) ? counts[i] : 0;
        if (i < NN) dinv[i] = rsqrtf((float)(v + 1));
        int x = wave_incl_scan(v, lane);
        __syncthreads();  // ws reusable across c iterations
        if (lane == 63) ws[wv] = x;
        __syncthreads();
        int off = 0;
        for (int j = 0; j < wv; ++j) off += ws[j];
        if (i < NN) rowptr[i] = off + x - v;
        if (tid == 255) bsum[c] = off + x;
    }
    gg.sync();
    // P3: scan chunk sums (block 0 only; NCHUNK <= 256)
    if (bid == 0) {
        int v = (tid < NCHUNK) ? bsum[tid] : 0;
        int x = wave_incl_scan(v, lane);
        if (lane == 63) ws[wv] = x;
        __syncthreads();
        int off = 0;
        for (int j = 0; j < wv; ++j) off += ws[j];
        if (tid < NCHUNK) bsum[tid] = off + x - v;
    }
    gg.sync();
    // P4: add chunk offsets; zero cursor (counts reused)
    for (int i = gtid; i < NN; i += gsz) {
        rowptr[i] += bsum[i >> 8];
        counts[i] = 0;
    }
    if (gtid == 0) rowptr[NN] = NE;
    gg.sync();
    // P5: CSR fill (nontemporal store — csr not re-read in this kernel)
    for (int e = gtid; e < NE; e += gsz) {
        int s = edge[e], d = edge[NE + e];
        int p = rowptr[d] + atomicAdd(&counts[d], 1);
        v2i t = {s, __float_as_int(dinv[s] * dinv[d])};
        __builtin_nontemporal_store(t, (v2i*)&csr[p]);
    }
}

// ---- fallback prep pieces (round-4 chain) ----

__global__ __launch_bounds__(256) void k_zero(int* __restrict__ p, int n) {
    int i = blockIdx.x * 256 + threadIdx.x;
    if (i < n) p[i] = 0;
}

__global__ __launch_bounds__(256) void k_count(const int* __restrict__ edge,
                                               int* __restrict__ counts) {
    int e = blockIdx.x * 256 + threadIdx.x;
    if (e < NE) atomicAdd(&counts[edge[NE + e]], 1);
}

__global__ __launch_bounds__(256) void k_scan1(const int* __restrict__ counts,
                                               int* __restrict__ rowptr,
                                               int* __restrict__ bsum,
                                               float* __restrict__ dinv) {
    __shared__ int ws[4];
    int tid = threadIdx.x;
    int i = blockIdx.x * 256 + tid;
    int lane = tid & 63, wv = tid >> 6;
    int v = (i < NN) ? counts[i] : 0;
    if (i < NN) dinv[i] = rsqrtf((float)(v + 1));
    int x = wave_incl_scan(v, lane);
    if (lane == 63) ws[wv] = x;
    __syncthreads();
    int off = 0;
    for (int j = 0; j < wv; ++j) off += ws[j];
    if (i < NN) rowptr[i] = off + x - v;
    if (tid == 255) bsum[blockIdx.x] = off + x;
}

__global__ __launch_bounds__(256) void k_scan2(int* __restrict__ bsum, int n) {
    __shared__ int ws[4];
    int tid = threadIdx.x;
    int lane = tid & 63, wv = tid >> 6;
    int v = (tid < n) ? bsum[tid] : 0;
    int x = wave_incl_scan(v, lane);
    if (lane == 63) ws[wv] = x;
    __syncthreads();
    int off = 0;
    for (int j = 0; j < wv; ++j) off += ws[j];
    __syncthreads();
    if (tid < n) bsum[tid] = off + x - v;
}

__global__ __launch_bounds__(256) void k_scan3(int* __restrict__ rowptr,
                                               const int* __restrict__ bsum,
                                               int* __restrict__ cursor) {
    int i = blockIdx.x * 256 + threadIdx.x;
    if (i < NN) {
        rowptr[i] += bsum[blockIdx.x];
        cursor[i] = 0;
    }
    if (i == 0) rowptr[NN] = NE;
}

__global__ __launch_bounds__(256) void k_fill(const int* __restrict__ edge,
                                              const int* __restrict__ rowptr,
                                              int* __restrict__ cursor,
                                              const float* __restrict__ dinv,
                                              int2* __restrict__ csr) {
    int e = blockIdx.x * 256 + threadIdx.x;
    if (e >= NE) return;
    int s = edge[e], d = edge[NE + e];
    int p = rowptr[d] + atomicAdd(&cursor[d], 1);
    v2i t = {s, __float_as_int(dinv[s] * dinv[d])};
    __builtin_nontemporal_store(t, (v2i*)&csr[p]);
}

// ========== dense: H[N,128] @ W[128,128] -> T (round-4 BK=32 SGEMM) ==========

__global__ __launch_bounds__(256) void k_matmul128(const float* __restrict__ H,
                                                   const float* __restrict__ W,
                                                   float* __restrict__ T) {
    __shared__ float As[BK * 128];
    __shared__ float Bs[BK * 128];
    int tid = threadIdx.x;
    int lane = tid & 63, w = tid >> 6;
    int wr = lane >> 3, wc = lane & 7;
    int wy = w >> 1, wx = w & 1;
    int lr0 = wy * 64 + wr * 8;
    int lc0 = wx * 64 + wc * 8;
    int rowBase = blockIdx.x * 128;

    int sa_row = tid >> 1;
    int sa_k = (tid & 1) * 16;
    int sa_grow = rowBase + sa_row;
    if (sa_grow >= NN) sa_grow = NN - 1;

    float acc[8][8];
#pragma unroll
    for (int i = 0; i < 8; ++i)
#pragma unroll
        for (int j = 0; j < 8; ++j) acc[i][j] = 0.f;

    for (int k0 = 0; k0 < HID; k0 += BK) {
        const float4* hsrc = (const float4*)(H + (size_t)sa_grow * HID + k0 + sa_k);
        float4 a0 = hsrc[0], a1 = hsrc[1], a2 = hsrc[2], a3 = hsrc[3];
        const float4* wsrc = (const float4*)(W + (size_t)k0 * HID);
        float4 b0 = wsrc[tid], b1 = wsrc[tid + 256], b2 = wsrc[tid + 512], b3 = wsrc[tid + 768];
        __syncthreads();
        As[(sa_k + 0) * 128 + sa_row] = a0.x;  As[(sa_k + 1) * 128 + sa_row] = a0.y;
        As[(sa_k + 2) * 128 + sa_row] = a0.z;  As[(sa_k + 3) * 128 + sa_row] = a0.w;
        As[(sa_k + 4) * 128 + sa_row] = a1.x;  As[(sa_k + 5) * 128 + sa_row] = a1.y;
        As[(sa_k + 6) * 128 + sa_row] = a1.z;  As[(sa_k + 7) * 128 + sa_row] = a1.w;
        As[(sa_k + 8) * 128 + sa_row] = a2.x;  As[(sa_k + 9) * 128 + sa_row] = a2.y;
        As[(sa_k + 10) * 128 + sa_row] = a2.z; As[(sa_k + 11) * 128 + sa_row] = a2.w;
        As[(sa_k + 12) * 128 + sa_row] = a3.x; As[(sa_k + 13) * 128 + sa_row] = a3.y;
        As[(sa_k + 14) * 128 + sa_row] = a3.z; As[(sa_k + 15) * 128 + sa_row] = a3.w;
        ((float4*)Bs)[tid] = b0;
        ((float4*)Bs)[tid + 256] = b1;
        ((float4*)Bs)[tid + 512] = b2;
        ((float4*)Bs)[tid + 768] = b3;
        __syncthreads();
#pragma unroll
        for (int kk = 0; kk < BK; ++kk) {
            float a[8], b[8];
            ((float4*)a)[0] = *(const float4*)&As[kk * 128 + lr0];
            ((float4*)a)[1] = *(const float4*)&As[kk * 128 + lr0 + 4];
            ((float4*)b)[0] = *(const float4*)&Bs[kk * 128 + lc0];
            ((float4*)b)[1] = *(const float4*)&Bs[kk * 128 + lc0 + 4];
#pragma unroll
            for (int i = 0; i < 8; ++i)
#pragma unroll
                for (int j = 0; j < 8; ++j) acc[i][j] += a[i] * b[j];
        }
    }
#pragma unroll
    for (int i = 0; i < 8; ++i) {
        int gr = rowBase + lr0 + i;
        if (gr < NN) {
            float4 o0 = {acc[i][0], acc[i][1], acc[i][2], acc[i][3]};
            float4 o1 = {acc[i][4], acc[i][5], acc[i][6], acc[i][7]};
            float4* dst = (float4*)(T + (size_t)gr * HID + lc0);
            dst[0] = o0;   // T is re-read by the gather: keep cached (no NT)
            dst[1] = o1;
        }
    }
}

// ============ sparse gather (round-5 proven core) + NT output stores ============

__global__ __launch_bounds__(256) void k_gather_agg(const float* __restrict__ T,
                                                    float* __restrict__ Hout,
                                                    const int* __restrict__ rowptr,
                                                    const int2* __restrict__ csr,
                                                    const float* __restrict__ dinv,
                                                    const float* __restrict__ bias) {
    int lane = threadIdx.x & 63;
    int node = (blockIdx.x * 256 + threadIdx.x) >> 6;
    if (node >= NN) return;
    int slot = lane >> 4, c16 = lane & 15;

    int beg = rowptr[node], end = rowptr[node + 1];
    float4 acc0 = {0.f, 0.f, 0.f, 0.f}, acc1 = {0.f, 0.f, 0.f, 0.f};
    const int2 zed = make_int2(0, 0);

    int i = beg + slot;
    int2 e0 = (i < end) ? csr[i] : zed;
    int2 e1 = (i + 4 < end) ? csr[i + 4] : zed;
    for (; i < end; i += 8) {
        int2 p0 = (i + 8 < end) ? csr[i + 8] : zed;
        int2 p1 = (i + 12 < end) ? csr[i + 12] : zed;
        const float4* s0 = (const float4*)(T + (size_t)e0.x * HID);
        const float4* s1 = (const float4*)(T + (size_t)e1.x * HID);
        float4 u0 = s0[c16], u1 = s0[c16 + 16];
        float4 v0 = s1[c16], v1 = s1[c16 + 16];
        float w0 = __int_as_float(e0.y);
        float w1 = __int_as_float(e1.y);
        acc0.x += w0 * u0.x; acc0.y += w0 * u0.y; acc0.z += w0 * u0.z; acc0.w += w0 * u0.w;
        acc1.x += w0 * u1.x; acc1.y += w0 * u1.y; acc1.z += w0 * u1.z; acc1.w += w0 * u1.w;
        acc0.x += w1 * v0.x; acc0.y += w1 * v0.y; acc0.z += w1 * v0.z; acc0.w += w1 * v0.w;
        acc1.x += w1 * v1.x; acc1.y += w1 * v1.y; acc1.z += w1 * v1.z; acc1.w += w1 * v1.w;
        e0 = p0; e1 = p1;
    }
    acc0.x += __shfl_xor(acc0.x, 16, 64); acc0.y += __shfl_xor(acc0.y, 16, 64);
    acc0.z += __shfl_xor(acc0.z, 16, 64); acc0.w += __shfl_xor(acc0.w, 16, 64);
    acc1.x += __shfl_xor(acc1.x, 16, 64); acc1.y += __shfl_xor(acc1.y, 16, 64);
    acc1.z += __shfl_xor(acc1.z, 16, 64); acc1.w += __shfl_xor(acc1.w, 16, 64);
    acc0.x += __shfl_xor(acc0.x, 32, 64); acc0.y += __shfl_xor(acc0.y, 32, 64);
    acc0.z += __shfl_xor(acc0.z, 32, 64); acc0.w += __shfl_xor(acc0.w, 32, 64);
    acc1.x += __shfl_xor(acc1.x, 32, 64); acc1.y += __shfl_xor(acc1.y, 32, 64);
    acc1.z += __shfl_xor(acc1.z, 32, 64); acc1.w += __shfl_xor(acc1.w, 32, 64);

    if (slot == 0) {
        float sn = dinv[node];
        sn *= sn;
        const float4* trow = (const float4*)(T + (size_t)node * HID);
        float4 t0 = trow[c16], t1 = trow[c16 + 16];
        const float4* b4 = (const float4*)bias;
        float4 b0 = b4[c16], b1 = b4[c16 + 16];
        float4 r0, r1;
        r0.x = acc0.x + sn * t0.x + b0.x; r0.y = acc0.y + sn * t0.y + b0.y;
        r0.z = acc0.z + sn * t0.z + b0.z; r0.w = acc0.w + sn * t0.w + b0.w;
        r1.x = acc1.x + sn * t1.x + b1.x; r1.y = acc1.y + sn * t1.y + b1.y;
        r1.z = acc1.z + sn * t1.z + b1.z; r1.w = acc1.w + sn * t1.w + b1.w;
        r0.x = r0.x > 0.f ? r0.x : expm1f(r0.x);
        r0.y = r0.y > 0.f ? r0.y : expm1f(r0.y);
        r0.z = r0.z > 0.f ? r0.z : expm1f(r0.z);
        r0.w = r0.w > 0.f ? r0.w : expm1f(r0.w);
        r1.x = r1.x > 0.f ? r1.x : expm1f(r1.x);
        r1.y = r1.y > 0.f ? r1.y : expm1f(r1.y);
        r1.z = r1.z > 0.f ? r1.z : expm1f(r1.z);
        r1.w = r1.w > 0.f ? r1.w : expm1f(r1.w);
        // NT store: Hout isn't read in this kernel; keep L2 free for T rows
        float* dst = Hout + (size_t)node * HID;
        nt_store4(r0, dst + c16 * 4);
        nt_store4(r1, dst + (c16 + 16) * 4);
    }
}

// ================= output layer (128 -> 10) =================

__device__ __forceinline__ void dev_outmat_row(const float* __restrict__ H,
                                               const float* __restrict__ Ws,
                                               float* __restrict__ T2,
                                               int row, int c16) {
    const float* h = H + (size_t)row * HID;
    float acc[NCLS];
#pragma unroll
    for (int c = 0; c < NCLS; ++c) acc[c] = 0.f;
#pragma unroll
    for (int j = 0; j < 8; ++j) {
        float hv = h[c16 + 16 * j];
        const float* wr = &Ws[(c16 + 16 * j) * 11];
#pragma unroll
        for (int c = 0; c < NCLS; ++c) acc[c] += hv * wr[c];
    }
#pragma unroll
    for (int off = 8; off >= 1; off >>= 1) {
#pragma unroll
        for (int c = 0; c < NCLS; ++c) acc[c] += __shfl_xor(acc[c], off, 16);
    }
    if (c16 < NCLS) T2[(size_t)row * NCLS + c16] = acc[c16];
}

__device__ __forceinline__ void dev_outgather_node(const float* __restrict__ T2,
                                                   float* __restrict__ out,
                                                   const int* __restrict__ rowptr,
                                                   const int2* __restrict__ csr,
                                                   const float* __restrict__ dinv,
                                                   const float* __restrict__ bias,
                                                   int node, int lane) {
    int slot = lane >> 4, c = lane & 15;
    int beg = rowptr[node], end = rowptr[node + 1];
    float acc = 0.f;
    if (c < NCLS) {
        for (int i = beg + slot; i < end; i += 4) {
            int2 e = csr[i];
            acc += __int_as_float(e.y) * T2[(size_t)e.x * NCLS + c];
        }
    }
    acc += __shfl_xor(acc, 16, 64);
    acc += __shfl_xor(acc, 32, 64);
    if (slot == 0 && c < NCLS) {
        float sn = dinv[node];
        sn *= sn;
        out[node * NCLS + c] = acc + sn * T2[(size_t)node * NCLS + c] + bias[c];
    }
}

// cooperative: matmul_out then gather_out in one dispatch (both register-thin)
__global__ __launch_bounds__(256, 4) void k_out(const float* __restrict__ H,
                                                const float* __restrict__ W,
                                                const float* __restrict__ bias,
                                                const int* __restrict__ rowptr,
                                                const int2* __restrict__ csr,
                                                const float* __restrict__ dinv,
                                                float* __restrict__ T2,
                                                float* __restrict__ out) {
    cg::grid_group gg = cg::this_grid();
    __shared__ float Ws[128 * 11];
    int tid = threadIdx.x, bid = blockIdx.x;
    for (int m = tid; m < HID * NCLS; m += 256) {
        int k = m / NCLS, c = m - k * NCLS;
        Ws[k * 11 + c] = W[m];
    }
    __syncthreads();
    for (int g = bid; g < NGRP16; g += gridDim.x)
        dev_outmat_row(H, Ws, T2, g * 16 + (tid >> 4), tid & 15);
    gg.sync();
    for (int g = bid; g < NGRP4; g += gridDim.x)
        dev_outgather_node(T2, out, rowptr, csr, dinv, bias, g * 4 + (tid >> 6), tid & 63);
}

// ---- fallback output kernels ----

__global__ __launch_bounds__(256) void k_matmul_out(const float* __restrict__ H,
                                                    const float* __restrict__ W,
                                                    float* __restrict__ T2) {
    __shared__ float Ws[128 * 11];
    int tid = threadIdx.x;
    for (int m = tid; m < HID * NCLS; m += 256) {
        int k = m / NCLS, c = m - k * NCLS;
        Ws[k * 11 + c] = W[m];
    }
    __syncthreads();
    int row = (blockIdx.x * 256 + tid) >> 4;
    if (row >= NN) return;
    dev_outmat_row(H, Ws, T2, row, tid & 15);
}

__global__ __launch_bounds__(256) void k_gather_out(const float* __restrict__ T2,
                                                    float* __restrict__ out,
                                                    const int* __restrict__ rowptr,
                                                    const int2* __restrict__ csr,
                                                    const float* __restrict__ dinv,
                                                    const float* __restrict__ bias) {
    int node = (blockIdx.x * 256 + threadIdx.x) >> 6;
    if (node >= NN) return;
    dev_outgather_node(T2, out, rowptr, csr, dinv, bias, node, threadIdx.x & 63);
}

// ================= launch =================

extern "C" void kernel_launch(void* const* d_in, const int* in_sizes, int n_in,
                              void* d_out, int out_size, void* d_ws, size_t ws_size,
                              hipStream_t stream) {
    (void)in_sizes; (void)n_in; (void)out_size; (void)ws_size;
    const float* x       = (const float*)d_in[0];
    const int*   edge    = (const int*)d_in[1];   // [2, NE] int32
    const float* W_stack = (const float*)d_in[2];
    const float* b_stack = (const float*)d_in[3];
    const float* W_out   = (const float*)d_in[4];
    const float* b_out   = (const float*)d_in[5];
    float* out = (float*)d_out;

    char* ws = (char*)d_ws;
    const size_t bigbuf = (size_t)NN * HID * sizeof(float);  // 25.6 MB
    float* X      = (float*)ws;
    float* Y      = (float*)(ws + bigbuf);
    char*  p      = ws + 2 * bigbuf;
    int2*  csr    = (int2*)p;              p += sizeof(int2) * NE;
    float* dinv   = (float*)p;             p += sizeof(float) * NN;
    int*   rowptr = (int*)p;               p += sizeof(int) * (NN + 1);
    int*   counts = (int*)p;               p += sizeof(int) * NN;    // also cursor
    int*   bsum   = (int*)p;               p += sizeof(int) * 256;

    const int NB_N  = (NN + 255) / 256;        // 196
    const int NB_E  = (NE + 255) / 256;
    const int NB_MM = (NN + 127) / 128;        // 391
    const int NB_W  = (NN * 64 + 255) / 256;
    const int NB_O  = (NN * 16 + 255) / 256;

    // ---- prep: one cooperative dispatch (fallback: round-4 chain) ----
    bool prep_done = false;
    {
        int maxB = 0;
        if (hipOccupancyMaxActiveBlocksPerMultiprocessor(&maxB, k_prep, 256, 0) == hipSuccess
            && maxB >= 1) {
            int grid = maxB * 256;
            if (grid > 2048) grid = 2048;
            void* args[] = {(void*)&edge, (void*)&counts, (void*)&rowptr,
                            (void*)&bsum, (void*)&dinv,   (void*)&csr};
            if (hipLaunchCooperativeKernel((const void*)k_prep, dim3(grid), dim3(256),
                                           args, 0, stream) == hipSuccess)
                prep_done = true;
        }
    }
    if (!prep_done) {
        k_zero<<<NB_N, 256, 0, stream>>>(counts, NN);
        k_count<<<NB_E, 256, 0, stream>>>(edge, counts);
        k_scan1<<<NB_N, 256, 0, stream>>>(counts, rowptr, bsum, dinv);
        k_scan2<<<1, 256, 0, stream>>>(bsum, NB_N);
        k_scan3<<<NB_N, 256, 0, stream>>>(rowptr, bsum, counts);
        k_fill<<<NB_E, 256, 0, stream>>>(edge, rowptr, counts, dinv, csr);
    }

    // ---- 8 hidden layers (proven round-4 pair) ----
    const float* Hin = x;
    for (int l = 0; l < 8; ++l) {
        k_matmul128<<<NB_MM, 256, 0, stream>>>(Hin, W_stack + (size_t)l * HID * HID, Y);
        k_gather_agg<<<NB_W, 256, 0, stream>>>(Y, X, rowptr, csr, dinv,
                                               b_stack + (size_t)l * HID);
        Hin = X;
    }

    // ---- output layer: one cooperative dispatch (fallback: two kernels) ----
    bool out_done = false;
    {
        int maxB = 0;
        if (hipOccupancyMaxActiveBlocksPerMultiprocessor(&maxB, k_out, 256, 0) == hipSuccess
            && maxB >= 1) {
            int grid = maxB * 256;
            if (grid > 2048) grid = 2048;
            void* args[] = {(void*)&X,      (void*)&W_out, (void*)&b_out, (void*)&rowptr,
                            (void*)&csr,    (void*)&dinv,  (void*)&Y,     (void*)&out};
            if (hipLaunchCooperativeKernel((const void*)k_out, dim3(grid), dim3(256),
                                           args, 0, stream) == hipSuccess)
                out_done = true;
        }
    }
    if (!out_done) {
        k_matmul_out<<<NB_O, 256, 0, stream>>>(X, W_out, Y);
        k_gather_out<<<NB_W, 256, 0, stream>>>(Y, out, rowptr, csr, dinv, b_out);
    }
}